// Round 4
// baseline (281.868 us; speedup 1.0000x reference)
//
#include <hip/hip_runtime.h>
#include <stdint.h>

#define B_ 4
#define S_ 1024
#define D_ 2048
#define H_ 16
#define HD 128
#define E_ 6144

typedef short bf16x8 __attribute__((ext_vector_type(8)));
typedef float f32x4 __attribute__((ext_vector_type(4)));

__device__ __forceinline__ unsigned short f2bf(float f) {
  union { float f; unsigned u; } x; x.f = f;
  unsigned r = x.u + 0x7fffu + ((x.u >> 16) & 1u);
  return (unsigned short)(r >> 16);
}

__device__ __forceinline__ void gl_lds16(const void* g, void* l) {
  __builtin_amdgcn_global_load_lds(
      (const __attribute__((address_space(1))) void*)g,
      (__attribute__((address_space(3))) void*)l, 16, 0, 0);
}

// DPP cross-lane within the 16-lane row: single-cycle VALU, no LDS pipe.
template <int C>
__device__ __forceinline__ float dppf(float x) {
  union { float f; int i; } u; u.f = x;
  u.i = __builtin_amdgcn_update_dpp(u.i, u.i, C, 0xF, 0xF, true);
  return u.f;
}
__device__ __forceinline__ float red_max16(float v) {
  v = fmaxf(v, dppf<0xB1>(v));   // quad_perm [1,0,3,2]  (xor 1)
  v = fmaxf(v, dppf<0x4E>(v));   // quad_perm [2,3,0,1]  (xor 2)
  v = fmaxf(v, dppf<0x124>(v));  // row_ror:4
  v = fmaxf(v, dppf<0x128>(v));  // row_ror:8
  return v;
}
__device__ __forceinline__ float red_sum16(float v) {
  v += dppf<0xB1>(v);
  v += dppf<0x4E>(v);
  v += dppf<0x124>(v);
  v += dppf<0x128>(v);
  return v;
}

// ---- fused preprocessing: X cvt (2048 blk) | W cvt (3072 blk) | rope (256 blk)
__global__ __launch_bounds__(256) void prep(const float* __restrict__ X,
                                            short* __restrict__ Xt,
                                            const float* __restrict__ W,
                                            short* __restrict__ Wt,
                                            float2* __restrict__ tbl) {
  int blk = blockIdx.x;
  const int tid = threadIdx.x;

  if (blk >= 5120) {  // rope table: [s][j], j in [0,64)
    int idx = (blk - 5120) * 256 + tid;  // 65536
    int s = idx >> 6, j = idx & 63;
    float inv = exp2f(-0.20762050593045953f * (float)j);
    float a = (float)s * inv;
    tbl[idx] = make_float2(cosf(a), sinf(a));
    return;
  }

  const float* src;
  short* dst;
  if (blk < 2048) {
    src = X; dst = Xt;
  } else {
    blk -= 2048; src = W; dst = Wt;
  }

  __shared__ __align__(16) short L[128 * 40];
  const int kt = blk & 63, mt = blk >> 6;
  {
    int row = tid >> 1, half = tid & 1;
    const float* p = src + (size_t)(mt * 128 + row) * D_ + kt * 32 + half * 16;
    float4 v0 = *(const float4*)(p);
    float4 v1 = *(const float4*)(p + 4);
    float4 v2 = *(const float4*)(p + 8);
    float4 v3 = *(const float4*)(p + 12);
    union { short s[16]; int4 v[2]; } u;
    u.s[0] = (short)f2bf(v0.x);  u.s[1] = (short)f2bf(v0.y);
    u.s[2] = (short)f2bf(v0.z);  u.s[3] = (short)f2bf(v0.w);
    u.s[4] = (short)f2bf(v1.x);  u.s[5] = (short)f2bf(v1.y);
    u.s[6] = (short)f2bf(v1.z);  u.s[7] = (short)f2bf(v1.w);
    u.s[8] = (short)f2bf(v2.x);  u.s[9] = (short)f2bf(v2.y);
    u.s[10] = (short)f2bf(v2.z); u.s[11] = (short)f2bf(v2.w);
    u.s[12] = (short)f2bf(v3.x); u.s[13] = (short)f2bf(v3.y);
    u.s[14] = (short)f2bf(v3.z); u.s[15] = (short)f2bf(v3.w);
    int4* lp = (int4*)(L + row * 40 + half * 16);
    lp[0] = u.v[0];
    lp[1] = u.v[1];
  }
  __syncthreads();
  short* out = dst + (((size_t)(mt * 64 + kt)) << 12);
#pragma unroll
  for (int i = 0; i < 2; i++) {
    int ch = i * 256 + tid;
    int cc = ch & 15, qq = (ch >> 4) & 3, rt = ch >> 6;
    int4 v = *(const int4*)(L + (rt * 16 + cc) * 40 + qq * 8);
    *(int4*)(out + ch * 8) = v;
  }
}

// ---------------- QKV GEMM + bias + RoPE + fragment-order scatter ----------
// Model (corrected): MFMA = ~16.1 cyc/SIMD per 16x16x32; ds_read_b128 ~12 cyc
// effective (m134). Round-3 (256x128, 4w, reuse 2.67): per-CU-step LDS ~1650
// cyc vs MFMA 1030 -> LDS-issue-bound at 38.6% of peak (measured).
// This version: 256x384 tile, 8 waves (2M x 4N), per-wave 128x96:
// 48 MFMA from 8 A + 6 B reads (reuse 3.43). Per-SIMD MFMA 2x48x16.1=1546 cyc
// vs per-CU LDS ~1700 -> balanced; ceiling ~55-70%.
// N=384 = one full head (Q|K|V chunks 3bn..3bn+2): head = bn, epilogue does
// all 3 types per block. Grid 16x16 = 256 blocks = exactly 1/CU, single
// round, zero tail. LDS 120KB triple-buffer; stage depth 2; counted vmcnt(5)
// (never 0 mid-loop); ONE barrier/step; setprio around MFMA cluster.
//  step m: stage m+2 -> slot (m+2)%3 (last read step m-1; reads retired
//  pre-barrier) | ds_read slot m%3 | 48 MFMA | vmcnt(5) retires m+1's 5
//  chunks | barrier publishes slot (m+1)%3.
__global__ __launch_bounds__(512, 2) void qkv_gemm(
    const short* __restrict__ Xt, const short* __restrict__ Wt,
    const float* __restrict__ bq, const float2* __restrict__ rope,
    short* __restrict__ Qg, short* __restrict__ Kg, short* __restrict__ Vg) {
  __shared__ __align__(16) short As[3][2][4096];  // [slot][row-half]  48 KB
  __shared__ __align__(16) short Bs[3][3][4096];  // [slot][type]      72 KB

  const int tid = threadIdx.x;
  const int w = tid >> 6, lane = tid & 63;
  const int q = lane >> 4, c = lane & 15;
  const int wm = w >> 2, wn = w & 3;  // 2M x 4N
  const int bn = blockIdx.x, bm = blockIdx.y;

  const short* Ab = Xt + (size_t)(bm * 2) * 64 * 4096;  // row-chunks 2bm,2bm+1
  const short* Bb = Wt + (size_t)(bn * 3) * 64 * 4096;  // col-chunks 3bn..3bn+2

  // stage one K-step = 5 chunks x 8KB; 512 thr x 16B = 1 gl_lds per chunk
#define STAGE_STEP(sl, mm)                                                  \
  do {                                                                      \
    gl_lds16(Ab + ((size_t)(mm)) * 4096 + tid * 8, &As[sl][0][tid * 8]);    \
    gl_lds16(Ab + ((size_t)(64 + (mm))) * 4096 + tid * 8,                   \
             &As[sl][1][tid * 8]);                                          \
    gl_lds16(Bb + ((size_t)(mm)) * 4096 + tid * 8, &Bs[sl][0][tid * 8]);    \
    gl_lds16(Bb + ((size_t)(64 + (mm))) * 4096 + tid * 8,                   \
             &Bs[sl][1][tid * 8]);                                          \
    gl_lds16(Bb + ((size_t)(128 + (mm))) * 4096 + tid * 8,                  \
             &Bs[sl][2][tid * 8]);                                          \
  } while (0)

  f32x4 acc[8][3][2];  // [row-frag][type][rope-half] = 192 VGPR
#pragma unroll
  for (int i = 0; i < 8; i++)
#pragma unroll
    for (int t = 0; t < 3; t++)
#pragma unroll
      for (int jl = 0; jl < 2; jl++) acc[i][t][jl] = (f32x4){0.f, 0.f, 0.f, 0.f};

  // prologue: steps 0 (slot 0) and 1 (slot 1); 10 loads in flight
  STAGE_STEP(0, 0);
  STAGE_STEP(1, 1);
  asm volatile("s_waitcnt vmcnt(5)" ::: "memory");  // step-0 chunks landed
  __builtin_amdgcn_s_barrier();

  int s = 0;
  for (int m = 0; m < 64; m++) {
    if (m + 2 < 64) {
      int s2 = s + 2;
      if (s2 >= 3) s2 -= 3;
      STAGE_STEP(s2, m + 2);
    }

    bf16x8 bfr[3][2];
#pragma unroll
    for (int t = 0; t < 3; t++)
#pragma unroll
      for (int jl = 0; jl < 2; jl++)
        bfr[t][jl] = *(const bf16x8*)(&Bs[s][t][(wn + jl * 4) * 512 + lane * 8]);

    __builtin_amdgcn_s_setprio(1);
#pragma unroll
    for (int i = 0; i < 8; i++) {
      bf16x8 ai = *(const bf16x8*)(&As[s][wm][i * 512 + lane * 8]);
#pragma unroll
      for (int t = 0; t < 3; t++)
#pragma unroll
        for (int jl = 0; jl < 2; jl++)
          acc[i][t][jl] = __builtin_amdgcn_mfma_f32_16x16x32_bf16(
              ai, bfr[t][jl], acc[i][t][jl], 0, 0, 0);
    }
    __builtin_amdgcn_s_setprio(0);

    if (m < 62) asm volatile("s_waitcnt vmcnt(5)" ::: "memory");
    else        asm volatile("s_waitcnt vmcnt(0)" ::: "memory");
    __builtin_amdgcn_s_barrier();  // slot (m+1)%3 published to all waves

    s = (s == 2) ? 0 : s + 1;
  }
#undef STAGE_STEP

  // ---------------- epilogue: bias + RoPE + fragment-order scatter ----------
  // wave wn owns, per type t, col-frags {wn, wn+4} = cols wn*16+[0,16) and
  // +64: exactly one RoPE pair. head = bn.
  const int b_ = bm >> 2;
  const int bh = b_ * H_ + bn;
  const int sb = ((bm & 3) << 8) + wm * 128;  // wave's first seq row (128 rows)
  const int slab0 = sb >> 6;                  // first of two 64-row k/v slabs

  float bias[3][2];
#pragma unroll
  for (int t = 0; t < 3; t++)
#pragma unroll
    for (int jl = 0; jl < 2; jl++)
      bias[t][jl] = bq[bn * 384 + t * 128 + jl * 64 + wn * 16 + c];
#pragma unroll
  for (int i = 0; i < 8; i++)
#pragma unroll
    for (int t = 0; t < 3; t++)
#pragma unroll
      for (int jl = 0; jl < 2; jl++)
#pragma unroll
        for (int r = 0; r < 4; r++) acc[i][t][jl][r] += bias[t][jl];

  // RoPE on Q (t=0) and K (t=1)
#pragma unroll
  for (int i = 0; i < 8; i++)
#pragma unroll
    for (int r = 0; r < 4; r++) {
      int sg = sb + i * 16 + q * 4 + r;
      float2 cs = rope[sg * 64 + wn * 16 + c];
#pragma unroll
      for (int t = 0; t < 2; t++) {
        float x1 = acc[i][t][0][r], x2 = acc[i][t][1][r];
        acc[i][t][0][r] = x1 * cs.x - x2 * cs.y;
        acc[i][t][1][r] = x2 * cs.x + x1 * cs.y;
      }
    }

  // Q: row-major [bh][sg][128], pre-scaled by 1/sqrt(hd)
  {
    short* dst = Qg + (size_t)bh * S_ * HD;
#pragma unroll
    for (int i = 0; i < 8; i++)
#pragma unroll
      for (int r = 0; r < 4; r++) {
        int sg = sb + i * 16 + q * 4 + r;
        short* row = dst + (size_t)sg * HD;
#pragma unroll
        for (int jl = 0; jl < 2; jl++)
          row[jl * 64 + wn * 16 + c] =
              (short)f2bf(acc[i][0][jl][r] * 0.08838834764831845f);
      }
  }
  // K: fragment-order scatter (64-row slabs)
  {
    short* dstK = Kg + (size_t)bh * 16 * 8192 + (size_t)slab0 * 8192;
#pragma unroll
    for (int i = 0; i < 8; i++) {
      short* dsl = dstK + (i >> 2) * 8192;
      int ii = i & 3;
#pragma unroll
      for (int jl = 0; jl < 2; jl++) {
        int ctl = wn + jl * 4;
        int ks = ctl >> 1;
        int qqf = ((ctl & 1) << 1) + (c >> 3);
        short* p = dsl + (ks * 4 + ii) * 512 + qqf * 128 + (c & 7);
#pragma unroll
        for (int r = 0; r < 4; r++)
          p[(q * 4 + r) * 8] = (short)f2bf(acc[i][1][jl][r]);
      }
    }
  }
  // V: fragment-order scatter (64-row slabs)
  {
    short* dstV = Vg + (size_t)bh * 16 * 8192 + (size_t)slab0 * 8192;
#pragma unroll
    for (int i = 0; i < 8; i++) {
      short* dsl = dstV + (i >> 2) * 8192;
      int iw = i & 3;
#pragma unroll
      for (int jl = 0; jl < 2; jl++) {
        int ctl = wn + jl * 4;
#pragma unroll
        for (int r = 0; r < 4; r++) {
          int sl = q * 4 + r;
          int qqf = ((iw & 1) << 1) + (sl >> 3);
          dsl[((iw >> 1) * 8 + ctl) * 512 + qqf * 128 + c * 8 + (sl & 7)] =
              (short)f2bf(acc[i][2][jl][r]);
        }
      }
    }
  }
}

// ---------------- causal flash attention ----------------
// 512-thread blocks, q-tile 128 (8 waves x 16 q-rows), KT=64.
// Paired q-tiles (p, 7-p): every block does exactly 18 tile-iterations.
// K double-buffered; manual s_waitcnt vmcnt(N) + raw s_barrier pipelining.
__global__ __launch_bounds__(512) void flash_attn(
    const short* __restrict__ Qg, const short* __restrict__ Kg,
    const short* __restrict__ Vg, float* __restrict__ out) {
  __shared__ __align__(16) short Kb[2][8192];  // 32 KB
  __shared__ __align__(16) short Vb[8192];     // 16 KB
  __shared__ __align__(16) short Ps[8192];     // 16 KB, wave-private 2 KB regions

  const int tid = threadIdx.x;
  const int w = tid >> 6, lane = tid & 63;
  const int q = lane >> 4, c = lane & 15;
  const int bh = blockIdx.x, pp = blockIdx.y;  // XCD = bh%8 -> balanced
  const int b = bh >> 4, h = bh & 15;

  const short* Qh = Qg + (size_t)bh * S_ * HD;
  const short* Kh = Kg + (size_t)bh * 16 * 8192;
  const short* Vh = Vg + (size_t)bh * 16 * 8192;

#pragma unroll
  for (int ph = 0; ph < 2; ph++) {
    const int qt = ph ? 7 - pp : pp;
    const int q0 = qt * 128;
    const int n = 2 * qt + 2;  // 64-wide k-tiles covering k < q0+128

    bf16x8 aq[4];  // wave w owns q-rows q0 + w*16 + [0,16)
#pragma unroll
    for (int ks = 0; ks < 4; ks++)
      aq[ks] = *(const bf16x8*)(Qh + (size_t)(q0 + w * 16 + c) * HD + ks * 32 + q * 8);

    f32x4 o[8];
    float m_[4], l_[4];
#pragma unroll
    for (int tj = 0; tj < 8; tj++) o[tj] = (f32x4){0.f, 0.f, 0.f, 0.f};
#pragma unroll
    for (int r = 0; r < 4; r++) { m_[r] = -1e30f; l_[r] = 0.f; }

    // pre-stage K0 (2 instr/thread) then V0 (2 instr/thread)
#pragma unroll
    for (int i = 0; i < 2; i++) {
      int ch = i * 512 + tid;
      gl_lds16(Kh + ch * 8, &Kb[0][ch * 8]);
    }
#pragma unroll
    for (int i = 0; i < 2; i++) {
      int ch = i * 512 + tid;
      gl_lds16(Vh + ch * 8, Vb + ch * 8);
    }

    for (int it = 0; it < n; it++) {
      const int cur = it & 1;
      // wait K(it); newest 2 (V(it)) stay in flight
      asm volatile("s_waitcnt vmcnt(2)" ::: "memory");
      __builtin_amdgcn_s_barrier();  // B1: K(it) visible

      f32x4 s[4];
#pragma unroll
      for (int tj = 0; tj < 4; tj++) s[tj] = (f32x4){0.f, 0.f, 0.f, 0.f};
#pragma unroll
      for (int ks = 0; ks < 4; ks++)
#pragma unroll
        for (int tj = 0; tj < 4; tj++) {
          bf16x8 bk = *(const bf16x8*)(&Kb[cur][(ks * 4 + tj) * 512 + lane * 8]);
          s[tj] = __builtin_amdgcn_mfma_f32_16x16x32_bf16(aq[ks], bk, s[tj], 0, 0, 0);
        }

      // prefetch K(it+1); last reader of Kb[cur^1] finished before B2(it-1)
      if (it + 1 < n) {
#pragma unroll
        for (int i = 0; i < 2; i++) {
          int ch = i * 512 + tid;
          gl_lds16(Kh + (size_t)(it + 1) * 8192 + ch * 8, &Kb[cur ^ 1][ch * 8]);
        }
      }

      if (it >= 2 * qt) {  // diagonal-overlapping tiles: causal mask
#pragma unroll
        for (int tj = 0; tj < 4; tj++) {
          int kg = it * 64 + tj * 16 + c;
#pragma unroll
          for (int r = 0; r < 4; r++) {
            int qg = q0 + w * 16 + q * 4 + r;
            if (kg > qg) s[tj][r] = -1e30f;
          }
        }
      }

      // online softmax (DPP reductions within the 16-lane col group)
#pragma unroll
      for (int r = 0; r < 4; r++) {
        float mx = fmaxf(fmaxf(s[0][r], s[1][r]), fmaxf(s[2][r], s[3][r]));
        mx = red_max16(mx);
        float mn = fmaxf(m_[r], mx);
        float alpha = __expf(m_[r] - mn);
        m_[r] = mn;
        float rs = 0.f;
#pragma unroll
        for (int tj = 0; tj < 4; tj++) {
          float e = __expf(s[tj][r] - mn);
          s[tj][r] = e;
          rs += e;
        }
        rs = red_sum16(rs);
        l_[r] = l_[r] * alpha + rs;
#pragma unroll
        for (int tjd = 0; tjd < 8; tjd++) o[tjd][r] *= alpha;
      }

      // wait V(it): only K(it+1) prefetch (2, newer) may remain
      if (it + 1 < n)
        asm volatile("s_waitcnt vmcnt(2)" ::: "memory");
      else
        asm volatile("s_waitcnt vmcnt(0)" ::: "memory");
      __builtin_amdgcn_s_barrier();  // B2: V(it) visible

      // P: C-layout -> wave-private A-layout region (2 KB per wave)
#pragma unroll
      for (int tj = 0; tj < 4; tj++) {
        int base = w * 1024 + (tj >> 1) * 512 + (((tj & 1) << 1) + (c >> 3)) * 128 + (c & 7);
#pragma unroll
        for (int r = 0; r < 4; r++)
          Ps[base + (q * 4 + r) * 8] = (short)f2bf(s[tj][r]);
      }

#pragma unroll
      for (int ks2 = 0; ks2 < 2; ks2++) {
        bf16x8 ap = *(const bf16x8*)(Ps + w * 1024 + ks2 * 512 + lane * 8);
#pragma unroll
        for (int tjd = 0; tjd < 8; tjd++) {
          bf16x8 bv = *(const bf16x8*)(Vb + (ks2 * 8 + tjd) * 512 + lane * 8);
          o[tjd] = __builtin_amdgcn_mfma_f32_16x16x32_bf16(ap, bv, o[tjd], 0, 0, 0);
        }
      }
      __builtin_amdgcn_s_barrier();  // B3: all waves done reading Vb

      // stage V(it+1); drains at B2(it+1), overlapped by QK+softmax
      if (it + 1 < n) {
#pragma unroll
        for (int i = 0; i < 2; i++) {
          int ch = i * 512 + tid;
          gl_lds16(Vh + (size_t)(it + 1) * 8192 + ch * 8, Vb + ch * 8);
        }
      }
    }

#pragma unroll
    for (int r = 0; r < 4; r++) {
      float inv = 1.0f / l_[r];
      int sg = q0 + w * 16 + q * 4 + r;
      float* dst = out + (size_t)(b * S_ + sg) * D_ + h * HD;
#pragma unroll
      for (int tjd = 0; tjd < 8; tjd++) dst[tjd * 16 + c] = o[tjd][r] * inv;
    }
    // phase ends with zero outstanding staging loads (last iter stages nothing);
    // phase-1 B1's vmcnt(2) also drains these output stores (correct, cheap).
  }
}

extern "C" void kernel_launch(void* const* d_in, const int* in_sizes, int n_in,
                              void* d_out, int out_size, void* d_ws, size_t ws_size,
                              hipStream_t stream) {
  (void)in_sizes; (void)n_in; (void)out_size; (void)ws_size;
  const float* hs = (const float*)d_in[0];
  const float* wq = (const float*)d_in[1];
  const float* bq = (const float*)d_in[2];
  char* ws = (char*)d_ws;
  short* Xt = (short*)(ws);
  short* Wt = (short*)(ws + 16777216);
  short* Qg = (short*)(ws + 41943040);
  short* Kg = (short*)(ws + 58720256);
  short* Vg = (short*)(ws + 75497472);
  float2* tbl = (float2*)(ws + 92274688);

  hipLaunchKernelGGL(prep, dim3(5376), dim3(256), 0, stream, hs, Xt, wq, Wt, tbl);
  hipLaunchKernelGGL(qkv_gemm, dim3(16, 16), dim3(512), 0, stream, Xt, Wt, bq, tbl, Qg, Kg, Vg);
  hipLaunchKernelGGL(flash_attn, dim3(64, 4), dim3(512), 0, stream, Qg, Kg, Vg, (float*)d_out);
}

// Round 5
// 271.840 us; speedup vs baseline: 1.0369x; 1.0369x over previous
//
#include <hip/hip_runtime.h>
#include <stdint.h>

#define B_ 4
#define S_ 1024
#define D_ 2048
#define H_ 16
#define HD 128
#define E_ 6144

typedef short bf16x8 __attribute__((ext_vector_type(8)));
typedef float f32x4 __attribute__((ext_vector_type(4)));

__device__ __forceinline__ unsigned short f2bf(float f) {
  union { float f; unsigned u; } x; x.f = f;
  unsigned r = x.u + 0x7fffu + ((x.u >> 16) & 1u);
  return (unsigned short)(r >> 16);
}

__device__ __forceinline__ void gl_lds16(const void* g, void* l) {
  __builtin_amdgcn_global_load_lds(
      (const __attribute__((address_space(1))) void*)g,
      (__attribute__((address_space(3))) void*)l, 16, 0, 0);
}

// DPP cross-lane within the 16-lane row: single-cycle VALU, no LDS pipe.
template <int C>
__device__ __forceinline__ float dppf(float x) {
  union { float f; int i; } u; u.f = x;
  u.i = __builtin_amdgcn_update_dpp(u.i, u.i, C, 0xF, 0xF, true);
  return u.f;
}
__device__ __forceinline__ float red_max16(float v) {
  v = fmaxf(v, dppf<0xB1>(v));   // quad_perm [1,0,3,2]  (xor 1)
  v = fmaxf(v, dppf<0x4E>(v));   // quad_perm [2,3,0,1]  (xor 2)
  v = fmaxf(v, dppf<0x124>(v));  // row_ror:4
  v = fmaxf(v, dppf<0x128>(v));  // row_ror:8
  return v;
}
__device__ __forceinline__ float red_sum16(float v) {
  v += dppf<0xB1>(v);
  v += dppf<0x4E>(v);
  v += dppf<0x124>(v);
  v += dppf<0x128>(v);
  return v;
}

// ---- fused preprocessing: X cvt (2048 blk) | W cvt (3072 blk) | rope (256 blk)
__global__ __launch_bounds__(256) void prep(const float* __restrict__ X,
                                            short* __restrict__ Xt,
                                            const float* __restrict__ W,
                                            short* __restrict__ Wt,
                                            float2* __restrict__ tbl) {
  int blk = blockIdx.x;
  const int tid = threadIdx.x;

  if (blk >= 5120) {  // rope table: [s][j], j in [0,64)
    int idx = (blk - 5120) * 256 + tid;  // 65536
    int s = idx >> 6, j = idx & 63;
    float inv = exp2f(-0.20762050593045953f * (float)j);
    float a = (float)s * inv;
    tbl[idx] = make_float2(cosf(a), sinf(a));
    return;
  }

  const float* src;
  short* dst;
  if (blk < 2048) {
    src = X; dst = Xt;
  } else {
    blk -= 2048; src = W; dst = Wt;
  }

  __shared__ __align__(16) short L[128 * 40];
  const int kt = blk & 63, mt = blk >> 6;
  {
    int row = tid >> 1, half = tid & 1;
    const float* p = src + (size_t)(mt * 128 + row) * D_ + kt * 32 + half * 16;
    float4 v0 = *(const float4*)(p);
    float4 v1 = *(const float4*)(p + 4);
    float4 v2 = *(const float4*)(p + 8);
    float4 v3 = *(const float4*)(p + 12);
    union { short s[16]; int4 v[2]; } u;
    u.s[0] = (short)f2bf(v0.x);  u.s[1] = (short)f2bf(v0.y);
    u.s[2] = (short)f2bf(v0.z);  u.s[3] = (short)f2bf(v0.w);
    u.s[4] = (short)f2bf(v1.x);  u.s[5] = (short)f2bf(v1.y);
    u.s[6] = (short)f2bf(v1.z);  u.s[7] = (short)f2bf(v1.w);
    u.s[8] = (short)f2bf(v2.x);  u.s[9] = (short)f2bf(v2.y);
    u.s[10] = (short)f2bf(v2.z); u.s[11] = (short)f2bf(v2.w);
    u.s[12] = (short)f2bf(v3.x); u.s[13] = (short)f2bf(v3.y);
    u.s[14] = (short)f2bf(v3.z); u.s[15] = (short)f2bf(v3.w);
    int4* lp = (int4*)(L + row * 40 + half * 16);
    lp[0] = u.v[0];
    lp[1] = u.v[1];
  }
  __syncthreads();
  short* out = dst + (((size_t)(mt * 64 + kt)) << 12);
#pragma unroll
  for (int i = 0; i < 2; i++) {
    int ch = i * 256 + tid;
    int cc = ch & 15, qq = (ch >> 4) & 3, rt = ch >> 6;
    int4 v = *(const int4*)(L + (rt * 16 + cc) * 40 + qq * 8);
    *(int4*)(out + ch * 8) = v;
  }
}

// ---------------- QKV GEMM + bias + RoPE + fragment-order scatter ----------
// Evidence R0-R4: 2 independent blocks/CU -> 43% MfmaUtil; any 1-entity/CU
// lockstep -> 29-31%. Keep R3's shape (256x128 tile, 4 waves 2Mx2N, grid
// 48x16 = 3 clean rounds, 2 blocks/CU) and cut its LDS load + barrier count:
//  - B operand: LDS bypassed entirely. b-frags loaded global->reg (coalesced
//    16B/lane, W panel L2-resident, waves sharing wn hit L1). LDS now holds
//    only A: per-step traffic drops ~864 -> ~580 cyc; reads ride VMEM pipe.
//  - BK=64 (32 steps): half the barriers. A double-buffered 2x32KB = 64 KB
//    -> 2 blocks/CU preserved.
//  - depth-1 pipeline: top of step m stages A(m+1) (8 gl_lds) + loads b(m+1)
//    (8 HIP loads, can't cross the memory-clobber asm); end of step does
//    lgkmcnt(0) (ds_read vs next-step overwrite race) + vmcnt(0) + barrier.
//    The vmcnt(0) drain was issued ~1000 MFMA-cyc earlier -> fully hidden.
//  - register budget: acc 128 (AGPR) + bC/bN 64 + a/addr ~ unified <=256
//    -> 2 waves/SIMD (launch_bounds(256,2)), same envelope as R3's 244.
__global__ __launch_bounds__(256, 2) void qkv_gemm(
    const short* __restrict__ Xt, const short* __restrict__ Wt,
    const float* __restrict__ bq, const float2* __restrict__ rope,
    short* __restrict__ Qg, short* __restrict__ Kg, short* __restrict__ Vg) {
  __shared__ __align__(16) short As[2][2][2][4096];  // [slot][h][kk]  64 KB

  const int tid = threadIdx.x;
  const int w = tid >> 6, lane = tid & 63;
  const int q = lane >> 4, c = lane & 15;
  const int wm = w >> 1, wn = w & 1;
  const int bn = blockIdx.x, bm = blockIdx.y;

  const short* Ab = Xt + (size_t)(bm * 2) * 64 * 4096;  // 2 row-halves x 64 k-chunks
  const short* Bb = Wt + (size_t)bn * 64 * 4096;

  int ctl[4];
#pragma unroll
  for (int jl = 0; jl < 4; jl++) ctl[jl] = 2 * wn + (jl & 1) + ((jl >> 1) << 2);

  // stage A for step mm (k-chunks 2mm,2mm+1; both row-halves) -> slot sl
#define STAGE_A(sl, mm)                                                      \
  do {                                                                       \
    _Pragma("unroll") for (int h_ = 0; h_ < 2; h_++) {                       \
      _Pragma("unroll") for (int kk_ = 0; kk_ < 2; kk_++) {                  \
        const short* gs_ = Ab + ((size_t)(h_ * 64 + 2 * (mm) + kk_)) * 4096; \
        gl_lds16(gs_ + tid * 8, &As[sl][h_][kk_][tid * 8]);                  \
        gl_lds16(gs_ + 2048 + tid * 8, &As[sl][h_][kk_][2048 + tid * 8]);    \
      }                                                                      \
    }                                                                        \
  } while (0)

  // b-frags for step mm straight from global (plain loads; compiler-tracked)
#define LOAD_B(dst, mm)                                                      \
  do {                                                                       \
    _Pragma("unroll") for (int kk_ = 0; kk_ < 2; kk_++) {                    \
      _Pragma("unroll") for (int jl_ = 0; jl_ < 4; jl_++) {                  \
        dst[kk_][jl_] = *(const bf16x8*)(Bb +                                \
            (size_t)(2 * (mm) + kk_) * 4096 + ctl[jl_] * 512 + lane * 8);    \
      }                                                                      \
    }                                                                        \
  } while (0)

#define BODY(m, CUR, NXT)                                                    \
  do {                                                                       \
    if ((m) + 1 < 32) {                                                      \
      STAGE_A(((m) + 1) & 1, (m) + 1);                                       \
      LOAD_B(NXT, (m) + 1);                                                  \
    }                                                                        \
    __builtin_amdgcn_s_setprio(1);                                           \
    _Pragma("unroll") for (int kk_ = 0; kk_ < 2; kk_++) {                    \
      _Pragma("unroll") for (int i_ = 0; i_ < 8; i_++) {                     \
        bf16x8 ai_ =                                                         \
            *(const bf16x8*)(&As[(m) & 1][wm][kk_][i_ * 512 + lane * 8]);    \
        _Pragma("unroll") for (int jl_ = 0; jl_ < 4; jl_++) {                \
          acc[i_][jl_] = __builtin_amdgcn_mfma_f32_16x16x32_bf16(            \
              ai_, (CUR)[kk_][jl_], acc[i_][jl_], 0, 0, 0);                  \
        }                                                                    \
      }                                                                      \
    }                                                                        \
    __builtin_amdgcn_s_setprio(0);                                           \
    if ((m) + 1 < 32) {                                                      \
      asm volatile("s_waitcnt lgkmcnt(0)" ::: "memory");                     \
      asm volatile("s_waitcnt vmcnt(0)" ::: "memory");                       \
      __builtin_amdgcn_s_barrier();                                          \
    }                                                                        \
  } while (0)

  f32x4 acc[8][4];
#pragma unroll
  for (int i = 0; i < 8; i++)
#pragma unroll
    for (int jl = 0; jl < 4; jl++) acc[i][jl] = (f32x4){0.f, 0.f, 0.f, 0.f};

  bf16x8 bA[2][4], bB[2][4];

  // prologue: A(0) -> slot 0, b(0) -> bA
  STAGE_A(0, 0);
  LOAD_B(bA, 0);
  asm volatile("s_waitcnt vmcnt(0)" ::: "memory");
  __builtin_amdgcn_s_barrier();

  for (int mp = 0; mp < 16; mp++) {
    const int m0 = 2 * mp;
    BODY(m0, bA, bB);
    BODY(m0 + 1, bB, bA);
  }
#undef STAGE_A
#undef LOAD_B
#undef BODY

  // ---------------- epilogue: bias + RoPE + fragment-order scatter ----------
  const int head = bn / 3, typ = bn - head * 3;
  const int b_ = bm >> 2;
  const int bh = b_ * H_ + head;
  const int sb = ((bm & 3) << 8) + wm * 128;  // wave's first seq row (128 rows)
  const int slab0 = sb >> 6;                  // first of two 64-row k/v slabs

  float bias[4];
#pragma unroll
  for (int jl = 0; jl < 4; jl++) bias[jl] = bq[bn * 128 + ctl[jl] * 16 + c];
#pragma unroll
  for (int i = 0; i < 8; i++)
#pragma unroll
    for (int jl = 0; jl < 4; jl++)
#pragma unroll
      for (int r = 0; r < 4; r++) acc[i][jl][r] += bias[jl];

  if (typ < 2) {
#pragma unroll
    for (int i = 0; i < 8; i++)
#pragma unroll
      for (int r = 0; r < 4; r++) {
        int sg = sb + i * 16 + q * 4 + r;
#pragma unroll
        for (int jl = 0; jl < 2; jl++) {
          float2 cs = rope[sg * 64 + ctl[jl] * 16 + c];
          float x1 = acc[i][jl][r], x2 = acc[i][jl + 2][r];
          acc[i][jl][r] = x1 * cs.x - x2 * cs.y;
          acc[i][jl + 2][r] = x2 * cs.x + x1 * cs.y;
        }
      }
    if (typ == 0) {
      short* dst = Qg + (size_t)bh * S_ * HD;
#pragma unroll
      for (int i = 0; i < 8; i++)
#pragma unroll
        for (int r = 0; r < 4; r++) {
          int sg = sb + i * 16 + q * 4 + r;
          short* row = dst + (size_t)sg * HD;
#pragma unroll
          for (int jl = 0; jl < 4; jl++)
            row[ctl[jl] * 16 + c] = (short)f2bf(acc[i][jl][r] * 0.08838834764831845f);
        }
    } else {
      short* dstK = Kg + (size_t)bh * 16 * 8192 + (size_t)slab0 * 8192;
#pragma unroll
      for (int i = 0; i < 8; i++) {
        short* dsl = dstK + (i >> 2) * 8192;
        int ii = i & 3;
#pragma unroll
        for (int jl = 0; jl < 4; jl++) {
          int ks = ctl[jl] >> 1;
          int qqf = ((ctl[jl] & 1) << 1) + (c >> 3);
          short* p = dsl + (ks * 4 + ii) * 512 + qqf * 128 + (c & 7);
#pragma unroll
          for (int r = 0; r < 4; r++)
            p[(q * 4 + r) * 8] = (short)f2bf(acc[i][jl][r]);
        }
      }
    }
  } else {
    short* dstV = Vg + (size_t)bh * 16 * 8192 + (size_t)slab0 * 8192;
#pragma unroll
    for (int i = 0; i < 8; i++) {
      short* dsl = dstV + (i >> 2) * 8192;
      int iw = i & 3;
#pragma unroll
      for (int jl = 0; jl < 4; jl++)
#pragma unroll
        for (int r = 0; r < 4; r++) {
          int sl = q * 4 + r;
          int qqf = ((iw & 1) << 1) + (sl >> 3);
          dsl[((iw >> 1) * 8 + ctl[jl]) * 512 + qqf * 128 + c * 8 + (sl & 7)] =
              (short)f2bf(acc[i][jl][r]);
        }
    }
  }
}

// ---------------- causal flash attention ----------------
// 512-thread blocks, q-tile 128 (8 waves x 16 q-rows), KT=64.
// Paired q-tiles (p, 7-p): every block does exactly 18 tile-iterations.
// K double-buffered; manual s_waitcnt vmcnt(N) + raw s_barrier pipelining.
__global__ __launch_bounds__(512) void flash_attn(
    const short* __restrict__ Qg, const short* __restrict__ Kg,
    const short* __restrict__ Vg, float* __restrict__ out) {
  __shared__ __align__(16) short Kb[2][8192];  // 32 KB
  __shared__ __align__(16) short Vb[8192];     // 16 KB
  __shared__ __align__(16) short Ps[8192];     // 16 KB, wave-private 2 KB regions

  const int tid = threadIdx.x;
  const int w = tid >> 6, lane = tid & 63;
  const int q = lane >> 4, c = lane & 15;
  const int bh = blockIdx.x, pp = blockIdx.y;  // XCD = bh%8 -> balanced
  const int b = bh >> 4, h = bh & 15;

  const short* Qh = Qg + (size_t)bh * S_ * HD;
  const short* Kh = Kg + (size_t)bh * 16 * 8192;
  const short* Vh = Vg + (size_t)bh * 16 * 8192;

#pragma unroll
  for (int ph = 0; ph < 2; ph++) {
    const int qt = ph ? 7 - pp : pp;
    const int q0 = qt * 128;
    const int n = 2 * qt + 2;  // 64-wide k-tiles covering k < q0+128

    bf16x8 aq[4];  // wave w owns q-rows q0 + w*16 + [0,16)
#pragma unroll
    for (int ks = 0; ks < 4; ks++)
      aq[ks] = *(const bf16x8*)(Qh + (size_t)(q0 + w * 16 + c) * HD + ks * 32 + q * 8);

    f32x4 o[8];
    float m_[4], l_[4];
#pragma unroll
    for (int tj = 0; tj < 8; tj++) o[tj] = (f32x4){0.f, 0.f, 0.f, 0.f};
#pragma unroll
    for (int r = 0; r < 4; r++) { m_[r] = -1e30f; l_[r] = 0.f; }

    // pre-stage K0 (2 instr/thread) then V0 (2 instr/thread)
#pragma unroll
    for (int i = 0; i < 2; i++) {
      int ch = i * 512 + tid;
      gl_lds16(Kh + ch * 8, &Kb[0][ch * 8]);
    }
#pragma unroll
    for (int i = 0; i < 2; i++) {
      int ch = i * 512 + tid;
      gl_lds16(Vh + ch * 8, Vb + ch * 8);
    }

    for (int it = 0; it < n; it++) {
      const int cur = it & 1;
      // wait K(it); newest 2 (V(it)) stay in flight
      asm volatile("s_waitcnt vmcnt(2)" ::: "memory");
      __builtin_amdgcn_s_barrier();  // B1: K(it) visible

      f32x4 s[4];
#pragma unroll
      for (int tj = 0; tj < 4; tj++) s[tj] = (f32x4){0.f, 0.f, 0.f, 0.f};
#pragma unroll
      for (int ks = 0; ks < 4; ks++)
#pragma unroll
        for (int tj = 0; tj < 4; tj++) {
          bf16x8 bk = *(const bf16x8*)(&Kb[cur][(ks * 4 + tj) * 512 + lane * 8]);
          s[tj] = __builtin_amdgcn_mfma_f32_16x16x32_bf16(aq[ks], bk, s[tj], 0, 0, 0);
        }

      // prefetch K(it+1); last reader of Kb[cur^1] finished before B2(it-1)
      if (it + 1 < n) {
#pragma unroll
        for (int i = 0; i < 2; i++) {
          int ch = i * 512 + tid;
          gl_lds16(Kh + (size_t)(it + 1) * 8192 + ch * 8, &Kb[cur ^ 1][ch * 8]);
        }
      }

      if (it >= 2 * qt) {  // diagonal-overlapping tiles: causal mask
#pragma unroll
        for (int tj = 0; tj < 4; tj++) {
          int kg = it * 64 + tj * 16 + c;
#pragma unroll
          for (int r = 0; r < 4; r++) {
            int qg = q0 + w * 16 + q * 4 + r;
            if (kg > qg) s[tj][r] = -1e30f;
          }
        }
      }

      // online softmax (DPP reductions within the 16-lane col group)
#pragma unroll
      for (int r = 0; r < 4; r++) {
        float mx = fmaxf(fmaxf(s[0][r], s[1][r]), fmaxf(s[2][r], s[3][r]));
        mx = red_max16(mx);
        float mn = fmaxf(m_[r], mx);
        float alpha = __expf(m_[r] - mn);
        m_[r] = mn;
        float rs = 0.f;
#pragma unroll
        for (int tj = 0; tj < 4; tj++) {
          float e = __expf(s[tj][r] - mn);
          s[tj][r] = e;
          rs += e;
        }
        rs = red_sum16(rs);
        l_[r] = l_[r] * alpha + rs;
#pragma unroll
        for (int tjd = 0; tjd < 8; tjd++) o[tjd][r] *= alpha;
      }

      // wait V(it): only K(it+1) prefetch (2, newer) may remain
      if (it + 1 < n)
        asm volatile("s_waitcnt vmcnt(2)" ::: "memory");
      else
        asm volatile("s_waitcnt vmcnt(0)" ::: "memory");
      __builtin_amdgcn_s_barrier();  // B2: V(it) visible

      // P: C-layout -> wave-private A-layout region (2 KB per wave)
#pragma unroll
      for (int tj = 0; tj < 4; tj++) {
        int base = w * 1024 + (tj >> 1) * 512 + (((tj & 1) << 1) + (c >> 3)) * 128 + (c & 7);
#pragma unroll
        for (int r = 0; r < 4; r++)
          Ps[base + (q * 4 + r) * 8] = (short)f2bf(s[tj][r]);
      }

#pragma unroll
      for (int ks2 = 0; ks2 < 2; ks2++) {
        bf16x8 ap = *(const bf16x8*)(Ps + w * 1024 + ks2 * 512 + lane * 8);
#pragma unroll
        for (int tjd = 0; tjd < 8; tjd++) {
          bf16x8 bv = *(const bf16x8*)(Vb + (ks2 * 8 + tjd) * 512 + lane * 8);
          o[tjd] = __builtin_amdgcn_mfma_f32_16x16x32_bf16(ap, bv, o[tjd], 0, 0, 0);
        }
      }
      __builtin_amdgcn_s_barrier();  // B3: all waves done reading Vb

      // stage V(it+1); drains at B2(it+1), overlapped by QK+softmax
      if (it + 1 < n) {
#pragma unroll
        for (int i = 0; i < 2; i++) {
          int ch = i * 512 + tid;
          gl_lds16(Vh + (size_t)(it + 1) * 8192 + ch * 8, Vb + ch * 8);
        }
      }
    }

#pragma unroll
    for (int r = 0; r < 4; r++) {
      float inv = 1.0f / l_[r];
      int sg = q0 + w * 16 + q * 4 + r;
      float* dst = out + (size_t)(b * S_ + sg) * D_ + h * HD;
#pragma unroll
      for (int tjd = 0; tjd < 8; tjd++) dst[tjd * 16 + c] = o[tjd][r] * inv;
    }
    // phase ends with zero outstanding staging loads (last iter stages nothing);
    // phase-1 B1's vmcnt(2) also drains these output stores (correct, cheap).
  }
}

extern "C" void kernel_launch(void* const* d_in, const int* in_sizes, int n_in,
                              void* d_out, int out_size, void* d_ws, size_t ws_size,
                              hipStream_t stream) {
  (void)in_sizes; (void)n_in; (void)out_size; (void)ws_size;
  const float* hs = (const float*)d_in[0];
  const float* wq = (const float*)d_in[1];
  const float* bq = (const float*)d_in[2];
  char* ws = (char*)d_ws;
  short* Xt = (short*)(ws);
  short* Wt = (short*)(ws + 16777216);
  short* Qg = (short*)(ws + 41943040);
  short* Kg = (short*)(ws + 58720256);
  short* Vg = (short*)(ws + 75497472);
  float2* tbl = (float2*)(ws + 92274688);

  hipLaunchKernelGGL(prep, dim3(5376), dim3(256), 0, stream, hs, Xt, wq, Wt, tbl);
  hipLaunchKernelGGL(qkv_gemm, dim3(48, 16), dim3(256), 0, stream, Xt, Wt, bq, tbl, Qg, Kg, Vg);
  hipLaunchKernelGGL(flash_attn, dim3(64, 4), dim3(512), 0, stream, Qg, Kg, Vg, (float*)d_out);
}

// Round 6
// 261.486 us; speedup vs baseline: 1.0779x; 1.0396x over previous
//
#include <hip/hip_runtime.h>
#include <stdint.h>

#define B_ 4
#define S_ 1024
#define D_ 2048
#define H_ 16
#define HD 128
#define E_ 6144

typedef short bf16x8 __attribute__((ext_vector_type(8)));
typedef float f32x4 __attribute__((ext_vector_type(4)));

__device__ __forceinline__ unsigned short f2bf(float f) {
  union { float f; unsigned u; } x; x.f = f;
  unsigned r = x.u + 0x7fffu + ((x.u >> 16) & 1u);
  return (unsigned short)(r >> 16);
}

__device__ __forceinline__ void gl_lds16(const void* g, void* l) {
  __builtin_amdgcn_global_load_lds(
      (const __attribute__((address_space(1))) void*)g,
      (__attribute__((address_space(3))) void*)l, 16, 0, 0);
}

// DPP cross-lane within the 16-lane row: single-cycle VALU, no LDS pipe.
template <int C>
__device__ __forceinline__ float dppf(float x) {
  union { float f; int i; } u; u.f = x;
  u.i = __builtin_amdgcn_update_dpp(u.i, u.i, C, 0xF, 0xF, true);
  return u.f;
}
__device__ __forceinline__ float red_max16(float v) {
  v = fmaxf(v, dppf<0xB1>(v));   // quad_perm [1,0,3,2]  (xor 1)
  v = fmaxf(v, dppf<0x4E>(v));   // quad_perm [2,3,0,1]  (xor 2)
  v = fmaxf(v, dppf<0x124>(v));  // row_ror:4
  v = fmaxf(v, dppf<0x128>(v));  // row_ror:8
  return v;
}
__device__ __forceinline__ float red_sum16(float v) {
  v += dppf<0xB1>(v);
  v += dppf<0x4E>(v);
  v += dppf<0x124>(v);
  v += dppf<0x128>(v);
  return v;
}

// ---- fused preprocessing: X cvt (2048 blk) | W cvt (3072 blk) | rope (256 blk)
__global__ __launch_bounds__(256) void prep(const float* __restrict__ X,
                                            short* __restrict__ Xt,
                                            const float* __restrict__ W,
                                            short* __restrict__ Wt,
                                            float2* __restrict__ tbl) {
  int blk = blockIdx.x;
  const int tid = threadIdx.x;

  if (blk >= 5120) {  // rope table: [s][j], j in [0,64)
    int idx = (blk - 5120) * 256 + tid;  // 65536
    int s = idx >> 6, j = idx & 63;
    float inv = exp2f(-0.20762050593045953f * (float)j);
    float a = (float)s * inv;
    tbl[idx] = make_float2(cosf(a), sinf(a));
    return;
  }

  const float* src;
  short* dst;
  if (blk < 2048) {
    src = X; dst = Xt;
  } else {
    blk -= 2048; src = W; dst = Wt;
  }

  __shared__ __align__(16) short L[128 * 40];
  const int kt = blk & 63, mt = blk >> 6;
  {
    int row = tid >> 1, half = tid & 1;
    const float* p = src + (size_t)(mt * 128 + row) * D_ + kt * 32 + half * 16;
    float4 v0 = *(const float4*)(p);
    float4 v1 = *(const float4*)(p + 4);
    float4 v2 = *(const float4*)(p + 8);
    float4 v3 = *(const float4*)(p + 12);
    union { short s[16]; int4 v[2]; } u;
    u.s[0] = (short)f2bf(v0.x);  u.s[1] = (short)f2bf(v0.y);
    u.s[2] = (short)f2bf(v0.z);  u.s[3] = (short)f2bf(v0.w);
    u.s[4] = (short)f2bf(v1.x);  u.s[5] = (short)f2bf(v1.y);
    u.s[6] = (short)f2bf(v1.z);  u.s[7] = (short)f2bf(v1.w);
    u.s[8] = (short)f2bf(v2.x);  u.s[9] = (short)f2bf(v2.y);
    u.s[10] = (short)f2bf(v2.z); u.s[11] = (short)f2bf(v2.w);
    u.s[12] = (short)f2bf(v3.x); u.s[13] = (short)f2bf(v3.y);
    u.s[14] = (short)f2bf(v3.z); u.s[15] = (short)f2bf(v3.w);
    int4* lp = (int4*)(L + row * 40 + half * 16);
    lp[0] = u.v[0];
    lp[1] = u.v[1];
  }
  __syncthreads();
  short* out = dst + (((size_t)(mt * 64 + kt)) << 12);
#pragma unroll
  for (int i = 0; i < 2; i++) {
    int ch = i * 256 + tid;
    int cc = ch & 15, qq = (ch >> 4) & 3, rt = ch >> 6;
    int4 v = *(const int4*)(L + (rt * 16 + cc) * 40 + qq * 8);
    *(int4*)(out + ch * 8) = v;
  }
}

// ---------------- QKV GEMM + bias + RoPE + fragment-order scatter ----------
// R3 structure (best measured: 107 us, MfmaUtil 43%): 4 waves (2M x 2N),
// per-wave 128x64 (acc[8][4]), block tile 256x128, BK=32, grid 48x16 = 768
// blocks, LDS 72KB triple-buffer -> 2 blocks/CU (key: desynchronized blocks
// fill each other's barrier stalls; 1-entity/CU variants all hit 29-31%).
// Depth-2 prefetch, counted vmcnt(6) never drained mid-loop, 1 barrier/step.
__global__ __launch_bounds__(256, 2) void qkv_gemm(
    const short* __restrict__ Xt, const short* __restrict__ Wt,
    const float* __restrict__ bq, const float2* __restrict__ rope,
    short* __restrict__ Qg, short* __restrict__ Kg, short* __restrict__ Vg) {
  __shared__ __align__(16) short As[3][2][4096];  // [slot][row-half]  48 KB
  __shared__ __align__(16) short Bs[3][4096];     // [slot]            24 KB

  const int tid = threadIdx.x;
  const int w = tid >> 6, lane = tid & 63;
  const int q = lane >> 4, c = lane & 15;
  const int wm = w >> 1, wn = w & 1;
  const int bn = blockIdx.x, bm = blockIdx.y;

  const short* Ab = Xt + (size_t)(bm * 2) * 64 * 4096;  // 2 row-halves x 64 chunks
  const short* Bb = Wt + (size_t)bn * 64 * 4096;

  // stage one 4096-short chunk (8 KB) = 2 async 16B/lane loads per thread
#define STG(gsrc, ldst)                                              \
  do {                                                               \
    gl_lds16((gsrc) + tid * 8, (ldst) + tid * 8);                    \
    gl_lds16((gsrc) + 2048 + tid * 8, (ldst) + 2048 + tid * 8);      \
  } while (0)
#define STAGE_STEP(sl, mm)                                           \
  do {                                                               \
    STG(Ab + (size_t)(mm)*4096, &As[sl][0][0]);                      \
    STG(Ab + (size_t)(64 + (mm)) * 4096, &As[sl][1][0]);             \
    STG(Bb + (size_t)(mm)*4096, &Bs[sl][0]);                         \
  } while (0)

  int ctl[4];
#pragma unroll
  for (int jl = 0; jl < 4; jl++) ctl[jl] = 2 * wn + (jl & 1) + ((jl >> 1) << 2);

  f32x4 acc[8][4];
#pragma unroll
  for (int i = 0; i < 8; i++)
#pragma unroll
    for (int jl = 0; jl < 4; jl++) acc[i][jl] = (f32x4){0.f, 0.f, 0.f, 0.f};

  // prologue: chunks of steps 0 (slot 0) and 1 (slot 1); 12 loads in flight
  STAGE_STEP(0, 0);
  STAGE_STEP(1, 1);
  asm volatile("s_waitcnt vmcnt(6)" ::: "memory");  // step-0 chunks landed
  __builtin_amdgcn_s_barrier();

  int s = 0;
  for (int m = 0; m < 64; m++) {
    bf16x8 a[8], b[4];
#pragma unroll
    for (int i = 0; i < 8; i++)
      a[i] = *(const bf16x8*)(&As[s][wm][i * 512 + lane * 8]);
#pragma unroll
    for (int jl = 0; jl < 4; jl++)
      b[jl] = *(const bf16x8*)(&Bs[s][ctl[jl] * 512 + lane * 8]);

    if (m + 2 < 64) {
      int s2 = s + 2;
      if (s2 >= 3) s2 -= 3;
      STAGE_STEP(s2, m + 2);
    }

    __builtin_amdgcn_s_setprio(1);
#pragma unroll
    for (int i = 0; i < 8; i++)
#pragma unroll
      for (int jl = 0; jl < 4; jl++)
        acc[i][jl] = __builtin_amdgcn_mfma_f32_16x16x32_bf16(a[i], b[jl],
                                                             acc[i][jl], 0, 0, 0);
    __builtin_amdgcn_s_setprio(0);

    if (m < 62) asm volatile("s_waitcnt vmcnt(6)" ::: "memory");
    else        asm volatile("s_waitcnt vmcnt(0)" ::: "memory");
    __builtin_amdgcn_s_barrier();  // slot (m+1)%3 published to all waves

    s = (s == 2) ? 0 : s + 1;
  }
#undef STG
#undef STAGE_STEP

  // ---------------- epilogue: bias + RoPE + fragment-order scatter ----------
  const int head = bn / 3, typ = bn - head * 3;
  const int b_ = bm >> 2;
  const int bh = b_ * H_ + head;
  const int sb = ((bm & 3) << 8) + wm * 128;  // wave's first seq row (128 rows)
  const int slab0 = sb >> 6;                  // first of two 64-row k/v slabs

  float bias[4];
#pragma unroll
  for (int jl = 0; jl < 4; jl++) bias[jl] = bq[bn * 128 + ctl[jl] * 16 + c];
#pragma unroll
  for (int i = 0; i < 8; i++)
#pragma unroll
    for (int jl = 0; jl < 4; jl++)
#pragma unroll
      for (int r = 0; r < 4; r++) acc[i][jl][r] += bias[jl];

  if (typ < 2) {
#pragma unroll
    for (int i = 0; i < 8; i++)
#pragma unroll
      for (int r = 0; r < 4; r++) {
        int sg = sb + i * 16 + q * 4 + r;
#pragma unroll
        for (int jl = 0; jl < 2; jl++) {
          float2 cs = rope[sg * 64 + ctl[jl] * 16 + c];
          float x1 = acc[i][jl][r], x2 = acc[i][jl + 2][r];
          acc[i][jl][r] = x1 * cs.x - x2 * cs.y;
          acc[i][jl + 2][r] = x2 * cs.x + x1 * cs.y;
        }
      }
    if (typ == 0) {
      short* dst = Qg + (size_t)bh * S_ * HD;
#pragma unroll
      for (int i = 0; i < 8; i++)
#pragma unroll
        for (int r = 0; r < 4; r++) {
          int sg = sb + i * 16 + q * 4 + r;
          short* row = dst + (size_t)sg * HD;
#pragma unroll
          for (int jl = 0; jl < 4; jl++)
            row[ctl[jl] * 16 + c] = (short)f2bf(acc[i][jl][r] * 0.08838834764831845f);
        }
    } else {
      short* dstK = Kg + (size_t)bh * 16 * 8192 + (size_t)slab0 * 8192;
#pragma unroll
      for (int i = 0; i < 8; i++) {
        short* dsl = dstK + (i >> 2) * 8192;
        int ii = i & 3;
#pragma unroll
        for (int jl = 0; jl < 4; jl++) {
          int ks = ctl[jl] >> 1;
          int qqf = ((ctl[jl] & 1) << 1) + (c >> 3);
          short* p = dsl + (ks * 4 + ii) * 512 + qqf * 128 + (c & 7);
#pragma unroll
          for (int r = 0; r < 4; r++)
            p[(q * 4 + r) * 8] = (short)f2bf(acc[i][jl][r]);
        }
      }
    }
  } else {
    short* dstV = Vg + (size_t)bh * 16 * 8192 + (size_t)slab0 * 8192;
#pragma unroll
    for (int i = 0; i < 8; i++) {
      short* dsl = dstV + (i >> 2) * 8192;
      int iw = i & 3;
#pragma unroll
      for (int jl = 0; jl < 4; jl++)
#pragma unroll
        for (int r = 0; r < 4; r++) {
          int sl = q * 4 + r;
          int qqf = ((iw & 1) << 1) + (sl >> 3);
          dsl[((iw >> 1) * 8 + ctl[jl]) * 512 + qqf * 128 + c * 8 + (sl & 7)] =
              (short)f2bf(acc[i][jl][r]);
        }
    }
  }
}

// ---------------- causal flash attention ----------------
// Rebuilt for 2 blocks/CU (the R3-vs-R4 lesson: desynced co-resident blocks
// fill each other's barrier/serial-chain stalls; old flash was 1 block/CU).
// 256-thread / 4-wave blocks, q-tile 64 (wave w owns 16 q-rows), KT=64.
// Grid (64 bh, 8 pp) = 512 blocks = exactly 2/CU, zero tail. Paired q-tiles
// (pp, 15-pp): every block does exactly 17 tile-iterations. Same-bh blocks
// share an XCD (linear id stride 64 -> bh%8) for K/V L2 locality.
// K AND V double-buffered (32+32 KB) + Ps 8 KB = 72 KB -> 2 blocks/CU.
// 2 barriers/iter (old B3 eliminated): prefetch of K/V(it+1) is issued right
// after B1 (all waves' PV(it-1) provably complete there); counted vmcnt only.
__global__ __launch_bounds__(256, 2) void flash_attn(
    const short* __restrict__ Qg, const short* __restrict__ Kg,
    const short* __restrict__ Vg, float* __restrict__ out) {
  __shared__ __align__(16) short Kb[2][8192];  // 32 KB
  __shared__ __align__(16) short Vb[2][8192];  // 32 KB
  __shared__ __align__(16) short Ps[4096];     // 8 KB, wave-private 2 KB regions

  const int tid = threadIdx.x;
  const int w = tid >> 6, lane = tid & 63;
  const int q = lane >> 4, c = lane & 15;
  const int bh = blockIdx.x, pp = blockIdx.y;
  const int b = bh >> 4, h = bh & 15;

  const short* Qh = Qg + (size_t)bh * S_ * HD;
  const short* Kh = Kg + (size_t)bh * 16 * 8192;
  const short* Vh = Vg + (size_t)bh * 16 * 8192;

#pragma unroll
  for (int ph = 0; ph < 2; ph++) {
    const int qt = ph ? 15 - pp : pp;
    const int q0 = qt * 64;
    const int n = qt + 1;  // 64-wide k-tiles covering k < q0+64

    bf16x8 aq[4];  // wave w owns q-rows q0 + w*16 + [0,16)
#pragma unroll
    for (int ks = 0; ks < 4; ks++)
      aq[ks] = *(const bf16x8*)(Qh + (size_t)(q0 + w * 16 + c) * HD + ks * 32 + q * 8);

    f32x4 o[8];
    float m_[4], l_[4];
#pragma unroll
    for (int tjd = 0; tjd < 8; tjd++) o[tjd] = (f32x4){0.f, 0.f, 0.f, 0.f};
#pragma unroll
    for (int r = 0; r < 4; r++) { m_[r] = -1e30f; l_[r] = 0.f; }

    // prologue: stage K0 (4 instr/thread) then V0 (4 instr/thread)
#pragma unroll
    for (int i = 0; i < 4; i++) {
      int ch = i * 256 + tid;
      gl_lds16(Kh + ch * 8, &Kb[0][ch * 8]);
    }
#pragma unroll
    for (int i = 0; i < 4; i++) {
      int ch = i * 256 + tid;
      gl_lds16(Vh + ch * 8, &Vb[0][ch * 8]);
    }

    for (int it = 0; it < n; it++) {
      const int cur = it & 1;
      // retire K(it); V(it)'s 4 loads stay in flight
      asm volatile("s_waitcnt vmcnt(4)" ::: "memory");
      __builtin_amdgcn_s_barrier();  // B1: K(it) visible; all PV(it-1) done

      // prefetch K(it+1), V(it+1) into cur^1 buffers (safe: last readers of
      // cur^1 finished before B1 -- QK(it-1) pre-B2(it-1), PV(it-1) pre-B1)
      if (it + 1 < n) {
#pragma unroll
        for (int i = 0; i < 4; i++) {
          int ch = i * 256 + tid;
          gl_lds16(Kh + (size_t)(it + 1) * 8192 + ch * 8, &Kb[cur ^ 1][ch * 8]);
        }
#pragma unroll
        for (int i = 0; i < 4; i++) {
          int ch = i * 256 + tid;
          gl_lds16(Vh + (size_t)(it + 1) * 8192 + ch * 8, &Vb[cur ^ 1][ch * 8]);
        }
      }

      f32x4 s[4];
#pragma unroll
      for (int tj = 0; tj < 4; tj++) s[tj] = (f32x4){0.f, 0.f, 0.f, 0.f};
#pragma unroll
      for (int ks = 0; ks < 4; ks++)
#pragma unroll
        for (int tj = 0; tj < 4; tj++) {
          bf16x8 bk = *(const bf16x8*)(&Kb[cur][(ks * 4 + tj) * 512 + lane * 8]);
          s[tj] = __builtin_amdgcn_mfma_f32_16x16x32_bf16(aq[ks], bk, s[tj], 0, 0, 0);
        }

      if (it == qt) {  // diagonal tile: causal mask
#pragma unroll
        for (int tj = 0; tj < 4; tj++) {
          int kg = it * 64 + tj * 16 + c;
#pragma unroll
          for (int r = 0; r < 4; r++) {
            int qg = q0 + w * 16 + q * 4 + r;
            if (kg > qg) s[tj][r] = -1e30f;
          }
        }
      }

      // online softmax (DPP reductions within the 16-lane col group)
#pragma unroll
      for (int r = 0; r < 4; r++) {
        float mx = fmaxf(fmaxf(s[0][r], s[1][r]), fmaxf(s[2][r], s[3][r]));
        mx = red_max16(mx);
        float mn = fmaxf(m_[r], mx);
        float alpha = __expf(m_[r] - mn);
        m_[r] = mn;
        float rs = 0.f;
#pragma unroll
        for (int tj = 0; tj < 4; tj++) {
          float e = __expf(s[tj][r] - mn);
          s[tj][r] = e;
          rs += e;
        }
        rs = red_sum16(rs);
        l_[r] = l_[r] * alpha + rs;
#pragma unroll
        for (int tjd = 0; tjd < 8; tjd++) o[tjd][r] *= alpha;
      }

      // retire V(it): K(it+1)+V(it+1) (8 newer loads) may remain in flight
      if (it + 1 < n)
        asm volatile("s_waitcnt vmcnt(8)" ::: "memory");
      else
        asm volatile("s_waitcnt vmcnt(0)" ::: "memory");
      __builtin_amdgcn_s_barrier();  // B2: V(it) visible

      // P: C-layout -> wave-private A-layout region (2 KB per wave)
#pragma unroll
      for (int tj = 0; tj < 4; tj++) {
        int base = w * 1024 + (tj >> 1) * 512 + (((tj & 1) << 1) + (c >> 3)) * 128 + (c & 7);
#pragma unroll
        for (int r = 0; r < 4; r++)
          Ps[base + (q * 4 + r) * 8] = (short)f2bf(s[tj][r]);
      }

#pragma unroll
      for (int ks2 = 0; ks2 < 2; ks2++) {
        bf16x8 ap = *(const bf16x8*)(Ps + w * 1024 + ks2 * 512 + lane * 8);
#pragma unroll
        for (int tjd = 0; tjd < 8; tjd++) {
          bf16x8 bv = *(const bf16x8*)(&Vb[cur][(ks2 * 8 + tjd) * 512 + lane * 8]);
          o[tjd] = __builtin_amdgcn_mfma_f32_16x16x32_bf16(ap, bv, o[tjd], 0, 0, 0);
        }
      }
    }

#pragma unroll
    for (int r = 0; r < 4; r++) {
      float inv = 1.0f / l_[r];
      int sg = q0 + w * 16 + q * 4 + r;
      float* dst = out + (size_t)(b * S_ + sg) * D_ + h * HD;
#pragma unroll
      for (int tjd = 0; tjd < 8; tjd++) dst[tjd * 16 + c] = o[tjd][r] * inv;
    }
    // phase boundary: all waves' PV reads of Kb/Vb[0..1] must complete before
    // next phase's prologue overwrites Kb[0]/Vb[0].
    __builtin_amdgcn_s_barrier();
  }
}

extern "C" void kernel_launch(void* const* d_in, const int* in_sizes, int n_in,
                              void* d_out, int out_size, void* d_ws, size_t ws_size,
                              hipStream_t stream) {
  (void)in_sizes; (void)n_in; (void)out_size; (void)ws_size;
  const float* hs = (const float*)d_in[0];
  const float* wq = (const float*)d_in[1];
  const float* bq = (const float*)d_in[2];
  char* ws = (char*)d_ws;
  short* Xt = (short*)(ws);
  short* Wt = (short*)(ws + 16777216);
  short* Qg = (short*)(ws + 41943040);
  short* Kg = (short*)(ws + 58720256);
  short* Vg = (short*)(ws + 75497472);
  float2* tbl = (float2*)(ws + 92274688);

  hipLaunchKernelGGL(prep, dim3(5376), dim3(256), 0, stream, hs, Xt, wq, Wt, tbl);
  hipLaunchKernelGGL(qkv_gemm, dim3(48, 16), dim3(256), 0, stream, Xt, Wt, bq, tbl, Qg, Kg, Vg);
  hipLaunchKernelGGL(flash_attn, dim3(64, 8), dim3(256), 0, stream, Qg, Kg, Vg, (float*)d_out);
}